// Round 14
// baseline (790.700 us; speedup 1.0000x reference)
//
#include <hip/hip_runtime.h>
#include <hip/hip_bf16.h>
#include <math.h>

#define Dm 386
#define Hh 8
#define DHd 64
#define FFf 1544
#define FUS 3728
#define STOK 200
#define NTOK 201

typedef __attribute__((ext_vector_type(8))) short bf16x8;
typedef __attribute__((ext_vector_type(4))) float f32x4;

__device__ inline void gload16(const void* g, void* lds) {
  __builtin_amdgcn_global_load_lds((const __attribute__((address_space(1))) void*)g,
                                   (__attribute__((address_space(3))) void*)lds, 16, 0, 0);
}

__device__ inline short bfb(float v) {
  union { float f; unsigned u; } c; c.f = v;
  unsigned r = (c.u + 0x7fff + ((c.u >> 16) & 1)) >> 16;
  if ((c.u & 0x7f800000) == 0x7f800000) r = c.u >> 16;
  return (short)r;
}

// Staging swizzle (inverse of read-XOR key ((row&7)<<4) on bytes 4..6).
__device__ inline void stage_coords(int lane, int& sr, int& sg) {
  int o = lane * 16;
  int rhi = (o >> 7) & 7;
  int r2 = (o >> 8) & 1;
  int r0 = ((o >> 6) & 1) ^ r2;
  sr = (rhi << 1) | r0;
  sg = ((o >> 4) & 3) ^ (sr & 3);
}

// ---------------- fused misc prep: conv weights + rope table + cls write ----------------
__global__ void misc_prep_kernel(const float* __restrict__ cw, __hip_bfloat16* __restrict__ wt,
                                 float* __restrict__ ct, float* __restrict__ st,
                                 const float* __restrict__ cls, float* __restrict__ act) {
  int b = blockIdx.x, t = threadIdx.x;
  if (b < 50) {                       // conv weights -> bf16 [400][32]
    int idx = b * 256 + t;
    if (idx < 400 * 32) {
      int n = idx >> 5, k = idx & 31;
      float v = (n < Dm && k < 27) ? cw[n * 27 + k] : 0.f;
      wt[idx] = __float2bfloat16(v);
    }
  } else if (b < 76) {                // rope cos/sin table [208][32]
    int idx = (b - 50) * 256 + t;
    if (idx < 208 * 32) {
      int i = idx >> 5, d = idx & 31;
      float inv = exp2f((float)d * -0.41524101186f);
      float a = (float)i * inv;
      ct[idx] = cosf(a);
      st[idx] = sinf(a);
    }
  } else {                            // cls token write
    int idx = (b - 76) * 256 + t;
    if (idx < 8 * Dm) {
      int r = idx / Dm, d = idx - r * Dm;
      act[((size_t)r * NTOK + STOK) * Dm + d] = cls[d];
    }
  }
}

// ---------------- weight convert pack ----------------
// Concat layouts (offsets folded into Bt pointers by host):
//  - wo+wff share [512 n][2080 k] per layer (wo k 0..511, wff k 512..2079)
//  - ca_q+ca_ff1 share [3712 n][416 k] per layer (q rows 0..511, ff1 rows 512..3711)
//  - ca_kv: 4 layers contiguous -> one [512 n][416 k] matrix
struct CvtPack {
  const float* W[11];
  __hip_bfloat16* Bt[11];
};

// convert body: one 64(k) x 128(n) tile, 512 threads (4x float4 loads, 128B row stores).
__device__ void convert_body(int id, float* tile, const CvtPack& p) {
  static const int KK[11]    = {386, 512, 1544, 386, 512, 1544, 386, 386, 512, 386, 1544};
  static const int NN[11]    = {3728, 386, 386, 3728, 386, 386, 512, 128, 386, 3088, 386};
  static const int KPO[11]   = {416, 512, 1568, 416, 512, 1568, 416, 416, 512, 416, 1568};
  static const int KPOUT[11] = {416, 2080, 2080, 416, 2080, 2080, 416, 416, 2080, 416, 2080};
  static const int NTIL[11]  = {30, 4, 4, 30, 4, 4, 4, 1, 4, 25, 4};   // Np/128
  static const int LSTR[11]  = {1597440, 1064960, 1064960, 1597440, 1064960, 1064960,
                                1544192, 53248, 1064960, 1544192, 1064960};
  static const int CNT[11]   = {840, 128, 400, 840, 128, 400, 112, 28, 128, 700, 400};
  int wi = 0;
  while (wi < 10 && id >= CNT[wi]) { id -= CNT[wi]; ++wi; }
  int K = KK[wi], N = NN[wi];
  int ntil = NTIL[wi];
  int kpout = KPOUT[wi];
  int z = id & 3; id >>= 2;
  int kt = id / ntil, bx = id - kt * ntil;
  int k0 = kt * 64, n0 = bx * 128;
  const float* Wl = p.W[wi] + (size_t)z * K * N;
  __hip_bfloat16* Btl = p.Bt[wi] + (size_t)z * LSTR[wi];

  int tid = threadIdx.x;
  bool nfull = (n0 + 128 <= N);

  if (nfull && (N & 3) == 0) {
    int t4 = tid & 31, tk = tid >> 5;
    int nb = n0 + t4 * 4;
    #pragma unroll
    for (int j = 0; j < 4; ++j) {
      int kl = tk + 16 * j;
      int k = k0 + kl;
      float4 v = {0.f, 0.f, 0.f, 0.f};
      if (k < K) v = *(const float4*)(Wl + (size_t)k * N + nb);
      float* tr = tile + kl * 130 + t4 * 4;
      tr[0] = v.x; tr[1] = v.y; tr[2] = v.z; tr[3] = v.w;
    }
  } else {
    int t2 = tid & 63, tk = tid >> 6;
    int nb = n0 + t2 * 2;
    #pragma unroll
    for (int j = 0; j < 8; ++j) {
      int kl = tk + 8 * j;
      int k = k0 + kl;
      float2 v = {0.f, 0.f};
      if (k < K) {
        const float* src = Wl + (size_t)k * N + nb;
        if (nfull) {
          v = *(const float2*)src;
        } else {
          if (nb < N) v.x = src[0];
          if (nb + 1 < N) v.y = src[1];
        }
      }
      tile[kl * 130 + t2 * 2] = v.x;
      tile[kl * 130 + t2 * 2 + 1] = v.y;
    }
  }
  __syncthreads();

  int kv = KPO[wi] - k0; if (kv > 64) kv = 64;
  int tk8 = tid & 7;
  int nr = tid >> 3;
  if (tk8 * 8 < kv) {
    #pragma unroll
    for (int h = 0; h < 2; ++h) {
      int n = nr + 64 * h;
      __hip_bfloat16 out[8] __attribute__((aligned(16)));
      #pragma unroll
      for (int e = 0; e < 8; ++e)
        out[e] = __float2bfloat16(tile[(tk8 * 8 + e) * 130 + n]);
      *(int4*)(Btl + (size_t)(n0 + n) * kpout + k0 + tk8 * 8) = *(const int4*)out;
    }
  }
}

// conv body: one image, 8 waves. patches aliased by pooled (liveness-disjoint).
__device__ void conv_body(int img, char* smem,
                          const float* __restrict__ input, const __hip_bfloat16* __restrict__ wt,
                          const float* __restrict__ conv_b, float* __restrict__ act) {
  __hip_bfloat16* patches = (__hip_bfloat16*)smem;            // [368][40] = 29440
  float* pooled = (float*)smem;                               // [8][400] = 12800 (aliases patches)
  float* biasS = (float*)(smem + 29440);                      // [400] = 1600 (negated bias)

  int bi = img / 400, fi = img % 400;
  int srow = (fi < STOK) ? bi : (4 + bi);
  int tok = (fi < STOK) ? fi : (fi - STOK);
  float* dst = act + ((size_t)srow * NTOK + tok) * Dm;

  int tid = threadIdx.x;
  const float* img_base = input + (size_t)img * 4800;
  for (int i = tid; i < 400; i += 512) biasS[i] = (i < Dm) ? -conv_b[i] : 0.f;

  for (int p = tid; p < 368; p += 512) {
    short rowv[32] __attribute__((aligned(16)));
    #pragma unroll
    for (int k = 27; k < 32; ++k) rowv[k] = 0;
    if (p < 361) {
      int oy = p / 19, ox = p - oy * 19;
      const float* bp = img_base + (2 * oy) * 40 + 2 * ox;
      #pragma unroll
      for (int c = 0; c < 3; ++c) {
        #pragma unroll
        for (int ky = 0; ky < 3; ++ky) {
          const float* rp = bp + c * 1600 + ky * 40;
          #pragma unroll
          for (int kx = 0; kx < 3; ++kx)
            rowv[c * 9 + ky * 3 + kx] = bfb(rp[kx]);
        }
      }
    } else {
      #pragma unroll
      for (int k = 0; k < 27; ++k) rowv[k] = 0;
    }
    int4* dv = (int4*)(patches + p * 40);
    const int4* sv = (const int4*)rowv;
    #pragma unroll
    for (int q = 0; q < 4; ++q) dv[q] = sv[q];
  }
  __syncthreads();

  int lane = tid & 63, w = tid >> 6;
  int col = lane & 15, rgrp = lane >> 4;

  bf16x8 af[3];
  #pragma unroll
  for (int t = 0; t < 3; ++t) {
    int m = w * 3 + t;
    int row = (m < 23) ? (m * 16 + col) : 0;
    af[t] = *(const bf16x8*)&patches[row * 40 + rgrp * 8];
  }
  __syncthreads();   // patches fully consumed into registers; pooled may now overwrite it

  for (int n = 0; n < 25; ++n) {
    bf16x8 bfrag = *(const bf16x8*)&wt[(n * 16 + col) * 32 + rgrp * 8];
    float nb = biasS[n * 16 + col];
    f32x4 a0 = {0.f, 0.f, 0.f, 0.f}, a1 = {0.f, 0.f, 0.f, 0.f};
    a0 = __builtin_amdgcn_mfma_f32_16x16x32_bf16(af[0], bfrag, a0, 0, 0, 0);
    a1 = __builtin_amdgcn_mfma_f32_16x16x32_bf16(af[1], bfrag, a1, 0, 0, 0);
    float psum = 0.f;
    #pragma unroll
    for (int j = 0; j < 4; ++j) psum += fmaxf(a0[j], nb);
    if (w == 7) {
      #pragma unroll
      for (int j = 0; j < 4; ++j) {
        int rr = 352 + rgrp * 4 + j;
        psum += (rr < 361) ? fmaxf(a1[j], nb) : 0.f;
      }
    } else {
      #pragma unroll
      for (int j = 0; j < 4; ++j) psum += fmaxf(a1[j], nb);
      f32x4 a2 = {0.f, 0.f, 0.f, 0.f};
      a2 = __builtin_amdgcn_mfma_f32_16x16x32_bf16(af[2], bfrag, a2, 0, 0, 0);
      #pragma unroll
      for (int j = 0; j < 4; ++j) psum += fmaxf(a2[j], nb);
    }
    psum += __shfl_xor(psum, 16);
    psum += __shfl_xor(psum, 32);
    if (lane < 16) pooled[w * 400 + n * 16 + lane] = psum;
  }
  __syncthreads();
  for (int d = tid; d < Dm; d += 512) {
    float s = 0.f;
    #pragma unroll
    for (int ww = 0; ww < 8; ++ww) s += pooled[ww * 400 + d];
    dst[d] = s * (1.f / 361.f) + conv_b[d];
  }
}

// ---------------- fused prep: conv (1600) + weight convert (4104), interleaved 5:13 ----------------
__global__ __launch_bounds__(512) void prep_conv_kernel(
    CvtPack p, const float* __restrict__ input, const __hip_bfloat16* __restrict__ wt,
    const float* __restrict__ conv_b, float* __restrict__ act) {
  __shared__ __align__(16) char smem[33280];
  int bid = blockIdx.x;
  int g = bid / 18, r = bid - g * 18;
  if (r < 5) {
    conv_body(g * 5 + r, smem, input, wt, conv_b, act);
  } else {
    int cid = g * 13 + (r - 5);
    if (cid < 4104) convert_body(cid, (float*)smem, p);
  }
}

// ---------------- layernorm ----------------
__global__ __launch_bounds__(64) void ln_kernel(const float* __restrict__ x,
                                                const float* __restrict__ g,
                                                __hip_bfloat16* __restrict__ y) {
  size_t row = blockIdx.x;
  const float* xr = x + row * Dm;
  __hip_bfloat16* yr = y + row * 416;
  int t = threadIdx.x;
  float v[7];
  float lsum = 0.f, lsq = 0.f;
  #pragma unroll
  for (int j = 0; j < 7; ++j) {
    int c = t + 64 * j;
    float val = (c < Dm) ? xr[c] : 0.f;
    v[j] = val;
    lsum += val;
    lsq += val * val;
  }
  #pragma unroll
  for (int o = 32; o > 0; o >>= 1) { lsum += __shfl_xor(lsum, o); lsq += __shfl_xor(lsq, o); }
  float mean = lsum * (1.f / 386.f);
  float var = lsq * (1.f / 386.f) - mean * mean;
  float inv = rsqrtf(var + 1e-5f);
  #pragma unroll
  for (int j = 0; j < 7; ++j) {
    int c = t + 64 * j;
    if (c < 416) {
      float out = (c < Dm) ? (v[j] - mean) * inv * g[c] : 0.f;
      yr[c] = __float2bfloat16(out);
    }
  }
}

// ---------------- bf16 MFMA matmul 128x128 ----------------
// kvtile >= 0: that N-tile (covering [kvtile*128, +64)=K, [+64,+128)=V of the fused
// QKVFF output) additionally emits pre-roped bf16 K and bf16 V from registers.
// Rope pair (d, d^32) lives in the same thread: acc[m][n] <-> acc[m][n^2] (wc==0 waves).
template<bool ACC>
__global__ __launch_bounds__(256) void mfma_mm(
    const __hip_bfloat16* __restrict__ A, const __hip_bfloat16* __restrict__ Bt,
    float* __restrict__ C, int M, int N, int Kp,
    short* __restrict__ kout, short* __restrict__ vout,
    const float* __restrict__ ct, const float* __restrict__ st, int kvtile) {
  __shared__ short As[128 * 32];
  __shared__ short Bs[128 * 32];
  int tid = threadIdx.x;
  int lane = tid & 63, w = tid >> 6;
  int wr = w >> 1, wc = w & 1;
  int bm = blockIdx.y * 128, bn = blockIdx.x * 128;
  f32x4 acc[4][4] = {};

  int sr, sg;
  stage_coords(lane, sr, sg);
  const __hip_bfloat16* Abase = A + (size_t)(bm + w * 16 + sr) * Kp + sg * 8;
  const __hip_bfloat16* Bbase = Bt + (size_t)(bn + w * 16 + sr) * Kp + sg * 8;
  short* AsW1 = As + w * 512;
  short* AsW2 = As + 2048 + w * 512;
  short* BsW1 = Bs + w * 512;
  short* BsW2 = Bs + 2048 + w * 512;
  size_t rstep = (size_t)64 * Kp;
  int key = (lane & 7) << 4;
  int kg16 = (lane >> 4) * 16;

  for (int k0 = 0; k0 < Kp; k0 += 32) {
    gload16(Abase + k0, AsW1);
    gload16(Abase + k0 + rstep, AsW2);
    gload16(Bbase + k0, BsW1);
    gload16(Bbase + k0 + rstep, BsW2);
    __syncthreads();
    bf16x8 af[4], bfr[4];
    #pragma unroll
    for (int m = 0; m < 4; ++m) {
      int R = wr * 64 + m * 16 + (lane & 15);
      af[m] = *(const bf16x8*)((const char*)As + ((R * 64 + kg16) ^ key));
    }
    #pragma unroll
    for (int n = 0; n < 4; ++n) {
      int R = wc * 64 + n * 16 + (lane & 15);
      bfr[n] = *(const bf16x8*)((const char*)Bs + ((R * 64 + kg16) ^ key));
    }
    #pragma unroll
    for (int m = 0; m < 4; ++m)
      #pragma unroll
      for (int n = 0; n < 4; ++n)
        acc[m][n] = __builtin_amdgcn_mfma_f32_16x16x32_bf16(af[m], bfr[n], acc[m][n], 0, 0, 0);
    __syncthreads();
  }

  int col = lane & 15, rbase = (lane >> 4) * 4;
  #pragma unroll
  for (int m = 0; m < 4; ++m) {
    #pragma unroll
    for (int n = 0; n < 4; ++n) {
      #pragma unroll
      for (int j = 0; j < 4; ++j) {
        int gr = bm + wr * 64 + m * 16 + rbase + j;
        int gc = bn + wc * 64 + n * 16 + col;
        if (gr < M && gc < N) {
          size_t idx = (size_t)gr * N + gc;
          if (ACC) C[idx] += acc[m][n][j]; else C[idx] = acc[m][n][j];
        }
      }
    }
  }

  // K/V register epilogue: wc==0 waves hold K (rope), wc==1 hold V (convert).
  if ((int)blockIdx.x == kvtile) {
    #pragma unroll
    for (int m = 0; m < 4; ++m) {
      #pragma unroll
      for (int j = 0; j < 4; ++j) {
        int gr = bm + wr * 64 + m * 16 + rbase + j;
        if (gr >= M) continue;
        int i = gr % NTOK;
        if (wc == 0) {
          #pragma unroll
          for (int n = 0; n < 4; ++n) {
            int d = n * 16 + col;
            float cc = ct[i * 32 + (d & 31)];
            float ss = st[i * 32 + (d & 31)];
            float self = acc[m][n][j], part = acc[m][n ^ 2][j];
            float outv = (d < 32) ? self * cc - part * ss : self * cc + part * ss;
            kout[(size_t)gr * 64 + d] = bfb(outv);
          }
        } else {
          #pragma unroll
          for (int n = 0; n < 4; ++n) {
            int d = n * 16 + col;
            vout[(size_t)gr * 64 + d] = bfb(acc[m][n][j]);
          }
        }
      }
    }
  }
}

// ---------------- kv-projection GEMM: 64x64 tiles, writes bf16 [4][804][128] directly ----------------
// tile tx: layer = tx>>1, half = tx&1 (0=K cols, 1=V cols). No f32 C.
__global__ __launch_bounds__(256) void mfma_mm64kv(
    const __hip_bfloat16* __restrict__ A, const __hip_bfloat16* __restrict__ Bt,
    short* __restrict__ kvb, int M, int Kp) {
  __shared__ short As[64 * 32];
  __shared__ short Bs[64 * 32];
  int tid = threadIdx.x;
  int lane = tid & 63, w = tid >> 6;
  int wr = w >> 1, wc = w & 1;
  int bm = blockIdx.y * 64, bn = blockIdx.x * 64;
  f32x4 acc[2][2] = {};

  int sr, sg;
  stage_coords(lane, sr, sg);
  const __hip_bfloat16* Abase = A + (size_t)(bm + w * 16 + sr) * Kp + sg * 8;
  const __hip_bfloat16* Bbase = Bt + (size_t)(bn + w * 16 + sr) * Kp + sg * 8;
  short* AsW = As + w * 512;
  short* BsW = Bs + w * 512;
  int key = (lane & 7) << 4;
  int kg16 = (lane >> 4) * 16;

  for (int k0 = 0; k0 < Kp; k0 += 32) {
    gload16(Abase + k0, AsW);
    gload16(Bbase + k0, BsW);
    __syncthreads();
    bf16x8 af[2], bfr[2];
    #pragma unroll
    for (int m = 0; m < 2; ++m) {
      int R = wr * 32 + m * 16 + (lane & 15);
      af[m] = *(const bf16x8*)((const char*)As + ((R * 64 + kg16) ^ key));
    }
    #pragma unroll
    for (int n = 0; n < 2; ++n) {
      int R = wc * 32 + n * 16 + (lane & 15);
      bfr[n] = *(const bf16x8*)((const char*)Bs + ((R * 64 + kg16) ^ key));
    }
    #pragma unroll
    for (int m = 0; m < 2; ++m)
      #pragma unroll
      for (int n = 0; n < 2; ++n)
        acc[m][n] = __builtin_amdgcn_mfma_f32_16x16x32_bf16(af[m], bfr[n], acc[m][n], 0, 0, 0);
    __syncthreads();
  }

  int col = lane & 15, rbase = (lane >> 4) * 4;
  int tx = blockIdx.x, layer = tx >> 1, half = tx & 1;
  #pragma unroll
  for (int m = 0; m < 2; ++m) {
    #pragma unroll
    for (int n = 0; n < 2; ++n) {
      #pragma unroll
      for (int j = 0; j < 4; ++j) {
        int gr = bm + wr * 32 + m * 16 + rbase + j;
        int d = wc * 32 + n * 16 + col;
        if (gr < M)
          kvb[((size_t)layer * 804 + gr) * 128 + half * 64 + d] = bfb(acc[m][n][j]);
      }
    }
  }
}

// ---------------- split-K 64x64 with atomic accumulate ----------------
__global__ __launch_bounds__(256) void mfma_mm64a(
    const __hip_bfloat16* __restrict__ A, const __hip_bfloat16* __restrict__ Bt,
    float* __restrict__ C, int M, int N, int Kp, int chunk) {
  int kbeg = blockIdx.z * chunk;
  if (kbeg >= Kp) return;
  int kend = min(Kp, kbeg + chunk);
  __shared__ short As[64 * 32];
  __shared__ short Bs[64 * 32];
  int tid = threadIdx.x;
  int lane = tid & 63, w = tid >> 6;
  int wr = w >> 1, wc = w & 1;
  int bm = blockIdx.y * 64, bn = blockIdx.x * 64;
  f32x4 acc[2][2] = {};

  int sr, sg;
  stage_coords(lane, sr, sg);
  const __hip_bfloat16* Abase = A + (size_t)(bm + w * 16 + sr) * Kp + sg * 8;
  const __hip_bfloat16* Bbase = Bt + (size_t)(bn + w * 16 + sr) * Kp + sg * 8;
  short* AsW = As + w * 512;
  short* BsW = Bs + w * 512;
  int key = (lane & 7) << 4;
  int kg16 = (lane >> 4) * 16;

  for (int k0 = kbeg; k0 < kend; k0 += 32) {
    gload16(Abase + k0, AsW);
    gload16(Bbase + k0, BsW);
    __syncthreads();
    bf16x8 af[2], bfr[2];
    #pragma unroll
    for (int m = 0; m < 2; ++m) {
      int R = wr * 32 + m * 16 + (lane & 15);
      af[m] = *(const bf16x8*)((const char*)As + ((R * 64 + kg16) ^ key));
    }
    #pragma unroll
    for (int n = 0; n < 2; ++n) {
      int R = wc * 32 + n * 16 + (lane & 15);
      bfr[n] = *(const bf16x8*)((const char*)Bs + ((R * 64 + kg16) ^ key));
    }
    #pragma unroll
    for (int m = 0; m < 2; ++m)
      #pragma unroll
      for (int n = 0; n < 2; ++n)
        acc[m][n] = __builtin_amdgcn_mfma_f32_16x16x32_bf16(af[m], bfr[n], acc[m][n], 0, 0, 0);
    __syncthreads();
  }

  int col = lane & 15, rbase = (lane >> 4) * 4;
  #pragma unroll
  for (int m = 0; m < 2; ++m) {
    #pragma unroll
    for (int n = 0; n < 2; ++n) {
      #pragma unroll
      for (int j = 0; j < 4; ++j) {
        int gr = bm + wr * 32 + m * 16 + rbase + j;
        int gc = bn + wc * 32 + n * 16 + col;
        if (gr < M && gc < N) unsafeAtomicAdd(&C[(size_t)gr * N + gc], acc[m][n][j]);
      }
    }
  }
}

// ---------------- f32 -> bf16 activation convert with zero K-pad (vectorized) ----------------
__global__ void convert_a_kernel(const float* __restrict__ src, __hip_bfloat16* __restrict__ dst,
                                 int M, int K, int Kp) {
  int chunks = Kp >> 3;
  int idx = blockIdx.x * blockDim.x + threadIdx.x;
  if (idx >= M * chunks) return;
  int r = idx / chunks, ch = idx - r * chunks;
  int c = ch * 8;
  const float* sr = src + (size_t)r * K;
  __hip_bfloat16 out[8] __attribute__((aligned(16)));
  #pragma unroll
  for (int e = 0; e < 8; e += 2) {
    int cc = c + e;
    float2 v = {0.f, 0.f};
    if (cc + 1 < K) v = *(const float2*)(sr + cc);
    else if (cc < K) v.x = sr[cc];
    out[e] = __float2bfloat16(v.x);
    out[e + 1] = __float2bfloat16(v.y);
  }
  *(int4*)(dst + (size_t)r * Kp + c) = *(const int4*)out;
}

// ---------------- fused flash attention + silu ----------------
// K/V are pre-converted bf16 (K pre-roped for self-attn). Q stays f32 (rope applied here).
// Blocks [0, 26*nb): attention (O cols 0..511). Blocks [26*nb, ...): silu (cols 512..2079).
__global__ __launch_bounds__(256) void attn_silu_kernel(
    const float* __restrict__ Q, int qstride,
    const short* __restrict__ K, int kstride,
    const short* __restrict__ V, int vstride,
    __hip_bfloat16* __restrict__ O, int ostride,
    int causal, float scale,
    const float* __restrict__ ct, const float* __restrict__ st, int dorope,
    int nb, int rows, int x1off, int gateoff) {
  int nf = 26 * nb;
  int tid = threadIdx.x;

  if ((int)blockIdx.x >= nf) {
    // ---- silu role ----
    int idx = ((int)blockIdx.x - nf) * 256 + tid;
    if (idx >= rows * 196) return;
    int r = idx / 196, ch = idx - r * 196;
    int c = ch * 8;
    __hip_bfloat16 out[8] __attribute__((aligned(16)));
    if (c < FFf) {
      const float* sr = Q + (size_t)r * qstride;
      float4 xa = *(const float4*)(sr + x1off + c);
      float4 xb = *(const float4*)(sr + x1off + c + 4);
      float4 ga = *(const float4*)(sr + gateoff + c);
      float4 gb = *(const float4*)(sr + gateoff + c + 4);
      float xv[8] = {xa.x, xa.y, xa.z, xa.w, xb.x, xb.y, xb.z, xb.w};
      float gv[8] = {ga.x, ga.y, ga.z, ga.w, gb.x, gb.y, gb.z, gb.w};
      #pragma unroll
      for (int e = 0; e < 8; ++e) {
        float g = gv[e];
        out[e] = __float2bfloat16(g / (1.f + __expf(-g)) * xv[e]);
      }
    } else {
      #pragma unroll
      for (int e = 0; e < 8; ++e) out[e] = __float2bfloat16(0.f);
    }
    *(int4*)(O + 512 + (size_t)r * ostride + c) = *(const int4*)out;
    return;
  }

  // ---- attention role ----
  __shared__ __align__(16) char smembuf[59392];
  short* Ks  = (short*)smembuf;            // [208*64]   = 26624 B (dead after S loop)
  short* Ps  = (short*)smembuf;            // [4*16*232] = 29696 B (aliases Ks)
  short* VTs = (short*)(smembuf + 29696);  // [64*232]   = 29696 B

  int bb = blockIdx.x / 26;
  int i0 = (blockIdx.x % 26) * 8;
  int lane = tid & 63, w = tid >> 6;
  const float* Qb = Q + (size_t)bb * NTOK * qstride;
  const short* Kb = K + (size_t)bb * NTOK * kstride;
  const short* Vb = V + (size_t)bb * NTOK * vstride;

  int ntiles = causal ? min(13, (i0 + 7) / 16 + 1) : 13;
  int jstage = ntiles * 16;
  int jm = min(jstage, 201);

  {
    int4 z = {0, 0, 0, 0};
    int4* vt4 = (int4*)VTs;
    for (int idx = tid; idx < 64 * 232 * 2 / 16; idx += 256) vt4[idx] = z;
  }
  __syncthreads();

  // stage K rows (bf16, pre-roped): 4 threads/row x 32B
  for (int jj = tid >> 2; jj < jstage; jj += 64) {
    int q4 = tid & 3;
    short vk[16] __attribute__((aligned(16)));
    if (jj < 201) {
      const int4* kr = (const int4*)(Kb + (size_t)jj * kstride + q4 * 16);
      ((int4*)vk)[0] = kr[0];
      ((int4*)vk)[1] = kr[1];
    } else {
      #pragma unroll
      for (int e = 0; e < 16; ++e) vk[e] = 0;
    }
    #pragma unroll
    for (int f = 0; f < 4; ++f) {
      int colb = q4 * 32 + f * 8;
      *(short4*)((char*)Ks + (jj * 128 + (colb ^ ((jj & 7) << 4)))) = *(short4*)&vk[f * 4];
    }
  }
  // stage V^T (bf16)
  for (int jj = tid >> 3; jj < jm; jj += 32) {
    int e8 = (tid & 7) * 8;
    short vv[8] __attribute__((aligned(16)));
    *(int4*)vv = *(const int4*)(Vb + (size_t)jj * vstride + e8);
    #pragma unroll
    for (int e = 0; e < 8; ++e) VTs[(e8 + e) * 232 + jj] = vv[e];
  }

  // Q fragments with fused rope + scale
  int r = lane & 15, kg = lane >> 4;
  int rg = w * 16 + r;
  int iq = i0 + (rg >> 3);
  if (iq > 200) iq = 200;
  int h = rg & 7;
  const float* qr = Qb + (size_t)iq * qstride + h * 64 + kg * 8;
  float x1[8], x2[8];
  {
    float4 a0 = ((const float4*)qr)[0];
    float4 a1 = ((const float4*)(qr + 4))[0];
    float4 b0 = ((const float4*)(qr + 32))[0];
    float4 b1 = ((const float4*)(qr + 36))[0];
    x1[0] = a0.x; x1[1] = a0.y; x1[2] = a0.z; x1[3] = a0.w;
    x1[4] = a1.x; x1[5] = a1.y; x1[6] = a1.z; x1[7] = a1.w;
    x2[0] = b0.x; x2[1] = b0.y; x2[2] = b0.z; x2[3] = b0.w;
    x2[4] = b1.x; x2[5] = b1.y; x2[6] = b1.z; x2[7] = b1.w;
  }
  if (dorope) {
    const float* cr = ct + iq * 32 + kg * 8;
    const float* sr2 = st + iq * 32 + kg * 8;
    #pragma unroll
    for (int e = 0; e < 8; ++e) {
      float c = cr[e], s = sr2[e];
      float n1 = x1[e] * c - x2[e] * s;
      float n2 = x2[e] * c + x1[e] * s;
      x1[e] = n1; x2[e] = n2;
    }
  }
  bf16x8 aq[2];
  #pragma unroll
  for (int e = 0; e < 8; ++e) {
    aq[0][e] = bfb(x1[e] * scale);
    aq[1][e] = bfb(x2[e] * scale);
  }
  __syncthreads();

  // S = Q @ K^T
  int key = (lane & 7) << 4;
  f32x4 s[13];
  #pragma unroll
  for (int nt = 0; nt < 13; ++nt) {
    s[nt] = (f32x4){0.f, 0.f, 0.f, 0.f};
    if (nt < ntiles) {
      #pragma unroll
      for (int kt = 0; kt < 2; ++kt) {
        int row = nt * 16 + r;
        bf16x8 bk = *(const bf16x8*)((const char*)Ks + ((row * 128 + kt * 64 + kg * 16) ^ key));
        s[nt] = __builtin_amdgcn_mfma_f32_16x16x32_bf16(aq[kt], bk, s[nt], 0, 0, 0);
      }
    }
  }

  // mask + softmax
  int jcol = lane & 15;
  int ibase[4];
  #pragma unroll
  for (int reg = 0; reg < 4; ++reg) ibase[reg] = i0 + ((w * 16 + kg * 4 + reg) >> 3);

  f32x4 mx = {-1e30f, -1e30f, -1e30f, -1e30f};
  #pragma unroll
  for (int nt = 0; nt < 13; ++nt) {
    if (nt >= ntiles) continue;
    int j = nt * 16 + jcol;
    #pragma unroll
    for (int reg = 0; reg < 4; ++reg) {
      bool ok = (j <= 200) && (!causal || j <= ibase[reg]);
      float sv = ok ? s[nt][reg] : -1e30f;
      s[nt][reg] = sv;
      mx[reg] = fmaxf(mx[reg], sv);
    }
  }
  #pragma unroll
  for (int o = 1; o < 16; o <<= 1) {
    #pragma unroll
    for (int reg = 0; reg < 4; ++reg) mx[reg] = fmaxf(mx[reg], __shfl_xor(mx[reg], o));
  }
  f32x4 sm = {0.f, 0.f, 0.f, 0.f};
  #pragma unroll
  for (int nt = 0; nt < 13; ++nt) {
    if (nt >= ntiles) continue;
    #pragma unroll
    for (int reg = 0; reg < 4; ++reg) {
      float p = __expf(s[nt][reg] - mx[reg]);
      s[nt][reg] = p;
      sm[reg] += p;
    }
  }
  #pragma unroll
  for (int o = 1; o < 16; o <<= 1) {
    #pragma unroll
    for (int reg = 0; reg < 4; ++reg) sm[reg] += __shfl_xor(sm[reg], o);
  }
  f32x4 inv;
  #pragma unroll
  for (int reg = 0; reg < 4; ++reg) inv[reg] = 1.f / sm[reg];

  __syncthreads();   // all warps done reading Ks; Ps (aliased) may now be written

  short* Pw = Ps + w * 16 * 232;
  #pragma unroll
  for (int nt = 0; nt < 13; ++nt) {
    #pragma unroll
    for (int reg = 0; reg < 4; ++reg) {
      float p = (nt < ntiles) ? s[nt][reg] * inv[reg] : 0.f;
      Pw[(kg * 4 + reg) * 232 + nt * 16 + jcol] = bfb(p);
    }
  }
  #pragma unroll
  for (int e = 0; e < 4; ++e) Pw[r * 232 + 208 + kg * 4 + e] = 0;

  // O = P @ V
  int ktn = (jstage + 31) >> 5;
  f32x4 o[4] = {};
  #pragma unroll
  for (int kt = 0; kt < 7; ++kt) {
    if (kt >= ktn) continue;
    bf16x8 ap = *(const bf16x8*)((const char*)Pw + (r * 464 + kt * 64 + kg * 16));
    #pragma unroll
    for (int nt = 0; nt < 4; ++nt) {
      bf16x8 bv = *(const bf16x8*)((const char*)VTs + ((nt * 16 + r) * 464 + kt * 64 + kg * 16));
      o[nt] = __builtin_amdgcn_mfma_f32_16x16x32_bf16(ap, bv, o[nt], 0, 0, 0);
    }
  }

  #pragma unroll
  for (int nt = 0; nt < 4; ++nt) {
    #pragma unroll
    for (int reg = 0; reg < 4; ++reg) {
      int rc = w * 16 + kg * 4 + reg;
      int i = i0 + (rc >> 3);
      if (i < NTOK) {
        int hh = rc & 7;
        O[((size_t)bb * NTOK + i) * ostride + hh * 64 + nt * 16 + jcol] = __float2bfloat16(o[nt][reg]);
      }
    }
  }
}

// ---------------- head ----------------
__global__ __launch_bounds__(64) void head_kernel(const float* __restrict__ act,
                                                  const float* __restrict__ g,
                                                  const float* __restrict__ w,
                                                  float* __restrict__ out) {
  int bb = blockIdx.x;
  const float* xr = act + ((size_t)bb * NTOK + STOK) * Dm;
  int t = threadIdx.x;
  float v[7];
  float lsum = 0.f, lsq = 0.f;
  #pragma unroll
  for (int j = 0; j < 7; ++j) {
    int c = t + 64 * j;
    float val = (c < Dm) ? xr[c] : 0.f;
    v[j] = val;
    lsum += val;
    lsq += val * val;
  }
  #pragma unroll
  for (int o = 32; o > 0; o >>= 1) { lsum += __shfl_xor(lsum, o); lsq += __shfl_xor(lsq, o); }
  float mean = lsum * (1.f / 386.f);
  float var = lsq * (1.f / 386.f) - mean * mean;
  float inv = rsqrtf(var + 1e-5f);
  float d0 = 0.f, d1 = 0.f;
  #pragma unroll
  for (int j = 0; j < 7; ++j) {
    int c = t + 64 * j;
    if (c < Dm) {
      float xn = (v[j] - mean) * inv * g[c];
      d0 = fmaf(xn, w[2 * c], d0);
      d1 = fmaf(xn, w[2 * c + 1], d1);
    }
  }
  #pragma unroll
  for (int o = 32; o > 0; o >>= 1) { d0 += __shfl_xor(d0, o); d1 += __shfl_xor(d1, o); }
  if (t == 0) { out[2 * bb] = d0; out[2 * bb + 1] = d1; }
}

extern "C" void kernel_launch(void* const* d_in, const int* in_sizes, int n_in,
                              void* d_out, int out_size, void* d_ws, size_t ws_size,
                              hipStream_t stream) {
  const float* input     = (const float*)d_in[0];
  const float* conv_w    = (const float*)d_in[1];
  const float* conv_b    = (const float*)d_in[2];
  const float* cls_tok   = (const float*)d_in[3];
  const float* uni_ln    = (const float*)d_in[4];
  const float* uni_fused = (const float*)d_in[5];
  const float* uni_wo    = (const float*)d_in[6];
  const float* uni_wff   = (const float*)d_in[7];
  const float* mm_ln     = (const float*)d_in[8];
  const float* mm_fused  = (const float*)d_in[9];
  const float* mm_wo     = (const float*)d_in[10];
  const float* mm_wff    = (const float*)d_in[11];
  const float* ca_ln     = (const float*)d_in[12];
  const float* ca_q      = (const float*)d_in[13];
  const float* ca_kv     = (const float*)d_in[14];
  const float* ca_o      = (const float*)d_in[15];
  const float* ca_ff1    = (const float*)d_in[16];
  const float* ca_ff2    = (const float*)d_in[17];
  const float* logit_ln  = (const float*)d_in[18];
  const float* logit_w   = (const float*)d_in[19];
  (void)in_sizes; (void)n_in; (void)out_size; (void)ws_size;

  char* wsb = (char*)d_ws;
  size_t off = 0;
  auto alloc = [&](size_t bytes) { void* p = wsb + off; off += (bytes + 255) & ~(size_t)255; return p; };

  float* act   = (float*)alloc((size_t)8 * NTOK * Dm * 4);
  float* fbuf  = (float*)alloc((size_t)8 * NTOK * FUS * 4);
  float* ctab  = (float*)alloc((size_t)208 * 32 * 4);
  float* stab  = (float*)alloc((size_t)208 * 32 * 4);
  short* kbuf  = (short*)alloc((size_t)1608 * 64 * 2);   // pre-roped bf16 K (self-attn)
  short* vbuf  = (short*)alloc((size_t)1608 * 64 * 2);   // bf16 V (self-attn)
  short* ckvb  = (short*)alloc((size_t)4 * 804 * 128 * 2); // bf16 K|V per ca layer
  __hip_bfloat16* xnb   = (__hip_bfloat16*)alloc((size_t)1664 * 416 * 2);
  __hip_bfloat16* ahbuf = (__hip_bfloat16*)alloc((size_t)1664 * 2080 * 2);  // [attn(512) | silu(1568)]
  __hip_bfloat16* ctxb  = (__hip_bfloat16*)alloc((size_t)896 * 416 * 2);
  __hip_bfloat16* cwT   = (__hip_bfloat16*)alloc((size_t)400 * 32 * 2);

  size_t sF  = (size_t)3840 * 416;      // fused qkvff weights (uni/mm)
  size_t sOW = (size_t)512 * 2080;      // wo|wff K-concat per layer
  size_t sQF = (size_t)3712 * 416;      // ca q|ff1 N-concat per layer
  __hip_bfloat16* uF  = (__hip_bfloat16*)alloc(4 * sF * 2);
  __hip_bfloat16* uOW = (__hip_bfloat16*)alloc(4 * sOW * 2);
  __hip_bfloat16* mF  = (__hip_bfloat16*)alloc(4 * sF * 2);
  __hip_bfloat16* mOW = (__hip_bfloat16*)alloc(4 * sOW * 2);
  __hip_bfloat16* cQF = (__hip_bfloat16*)alloc(4 * sQF * 2);
  __hip_bfloat16* cKV = (__hip_bfloat16*)alloc((size_t)512 * 416 * 2);   // 4 layers contiguous
  __hip_bfloat16* cOF = (__hip_bfloat16*)alloc(4 * sOW * 2);

  CvtPack pk;
  pk.W[0] = uni_fused; pk.Bt[0] = uF;
  pk.W[1] = uni_wo;    pk.Bt[1] = uOW;
  pk.W[2] = uni_wff;   pk.Bt[2] = uOW + 512;        // K-offset 512 within 2080 rows
  pk.W[3] = mm_fused;  pk.Bt[3] = mF;
  pk.W[4] = mm_wo;     pk.Bt[4] = mOW;
  pk.W[5] = mm_wff;    pk.Bt[5] = mOW + 512;
  pk.W[6] = ca_q;      pk.Bt[6] = cQF;
  pk.W[7] = ca_kv;     pk.Bt[7] = cKV;
  pk.W[8] = ca_o;      pk.Bt[8] = cOF;
  pk.W[9] = ca_ff1;    pk.Bt[9] = cQF + (size_t)512 * 416;  // N-offset 512 rows
  pk.W[10] = ca_ff2;   pk.Bt[10] = cOF + 512;

  misc_prep_kernel<<<89, 256, 0, stream>>>(conv_w, cwT, ctab, stab, cls_tok, act);
  prep_conv_kernel<<<5760, 512, 0, stream>>>(pk, input, cwT, conv_b, act);

  // wide GEMM (mfma_mm); kvtile>=0 makes N-tile kvtile emit pre-roped bf16 K + bf16 V
  auto mmWf = [&](const __hip_bfloat16* A, const __hip_bfloat16* Bt, float* C,
                  int M, int N, int Kp, int kvtile) {
    dim3 g((N + 127) / 128, (M + 127) / 128);
    mfma_mm<false><<<g, 256, 0, stream>>>(A, Bt, C, M, N, Kp,
                                          kbuf, vbuf, ctab, stab, kvtile);
  };
  auto mmA = [&](const __hip_bfloat16* A, const __hip_bfloat16* Bt, float* C,
                 int M, int N, int Kp) {
    int gx = (N + 63) / 64, gy = (M + 63) / 64;
    int blocks = gx * gy;
    int ksteps = Kp / 32;
    int nz = (blocks >= 512) ? 1 : (512 + blocks - 1) / blocks;
    if (nz > ksteps) nz = ksteps;
    int chunk = ((ksteps + nz - 1) / nz) * 32;
    dim3 g(gx, gy, nz);
    mfma_mm64a<<<g, 256, 0, stream>>>(A, Bt, C, M, N, Kp, chunk);
  };

  // per-transformer-block: ln -> QKVFF GEMM (emits K/V bf16) -> {attn|silu} -> K-concat mmA
  auto run_ptb = [&](float* x, int nb, const float* g, const __hip_bfloat16* wfB,
                     const __hip_bfloat16* owB) {
    int M = nb * NTOK;
    ln_kernel<<<M, 64, 0, stream>>>(x, g, xnb);
    mmWf(xnb, wfB, fbuf, M, FUS, 416, 4);
    int nblk = 26 * nb + (M * 196 + 255) / 256;
    attn_silu_kernel<<<nblk, 256, 0, stream>>>(
        fbuf, FUS, kbuf, 64, vbuf, 64, ahbuf, 2080, 1, 0.125f,
        ctab, stab, 1, nb, M, 640, 2184);
    mmA(ahbuf, owB, x, M, Dm, 2080);
  };

  for (int i = 0; i < 4; ++i)
    run_ptb(act, 8, uni_ln + i * Dm, uF + i * sF, uOW + i * sOW);

  const float* ctx = act + (size_t)4 * NTOK * Dm;
  convert_a_kernel<<<(804 * 52 + 255) / 256, 256, 0, stream>>>(ctx, ctxb, 804, Dm, 416);
  // all 4 layers' kv projections in one GEMM, written bf16 directly: ckvb[layer][row][K|V]
  {
    dim3 g(8, 13);
    mfma_mm64kv<<<g, 256, 0, stream>>>(ctxb, cKV, ckvb, 804, 416);
  }

  for (int i = 0; i < 4; ++i) {
    run_ptb(act, 4, mm_ln + i * Dm, mF + i * sF, mOW + i * sOW);
    int M = 4 * NTOK;
    ln_kernel<<<M, 64, 0, stream>>>(act, ca_ln + i * Dm, xnb);
    // q (cols 0..511) and ff1 (cols 512..3711) in one N=3712 GEMM (no kv emit)
    mmWf(xnb, cQF + i * sQF, fbuf, M, 3712, 416, -1);
    int nblk = 26 * 4 + (M * 196 + 255) / 256;
    attn_silu_kernel<<<nblk, 256, 0, stream>>>(
        fbuf, 3712, ckvb + (size_t)i * 804 * 128, 128,
        ckvb + (size_t)i * 804 * 128 + 64, 128, ahbuf, 2080,
        0, 0.125f, ctab, stab, 0, 4, M, 512, 2056);
    mmA(ahbuf, cOF + i * sOW, act, M, Dm, 2080);
  }

  head_kernel<<<4, 64, 0, stream>>>(act, logit_ln, logit_w, (float*)d_out);
}

// Round 15
// 779.678 us; speedup vs baseline: 1.0141x; 1.0141x over previous
//
#include <hip/hip_runtime.h>
#include <hip/hip_bf16.h>
#include <math.h>

#define Dm 386
#define Hh 8
#define DHd 64
#define FFf 1544
#define FUS 3728
#define STOK 200
#define NTOK 201

typedef __attribute__((ext_vector_type(8))) short bf16x8;
typedef __attribute__((ext_vector_type(4))) float f32x4;

__device__ inline void gload16(const void* g, void* lds) {
  __builtin_amdgcn_global_load_lds((const __attribute__((address_space(1))) void*)g,
                                   (__attribute__((address_space(3))) void*)lds, 16, 0, 0);
}

__device__ inline short bfb(float v) {
  union { float f; unsigned u; } c; c.f = v;
  unsigned r = (c.u + 0x7fff + ((c.u >> 16) & 1)) >> 16;
  if ((c.u & 0x7f800000) == 0x7f800000) r = c.u >> 16;
  return (short)r;
}

// Staging swizzle (inverse of read-XOR key ((row&7)<<4) on bytes 4..6).
__device__ inline void stage_coords(int lane, int& sr, int& sg) {
  int o = lane * 16;
  int rhi = (o >> 7) & 7;
  int r2 = (o >> 8) & 1;
  int r0 = ((o >> 6) & 1) ^ r2;
  sr = (rhi << 1) | r0;
  sg = ((o >> 4) & 3) ^ (sr & 3);
}

// ---------------- fused misc prep: conv weights + rope table + cls write ----------------
__global__ void misc_prep_kernel(const float* __restrict__ cw, __hip_bfloat16* __restrict__ wt,
                                 float* __restrict__ ct, float* __restrict__ st,
                                 const float* __restrict__ cls, float* __restrict__ act) {
  int b = blockIdx.x, t = threadIdx.x;
  if (b < 50) {                       // conv weights -> bf16 [400][32]
    int idx = b * 256 + t;
    if (idx < 400 * 32) {
      int n = idx >> 5, k = idx & 31;
      float v = (n < Dm && k < 27) ? cw[n * 27 + k] : 0.f;
      wt[idx] = __float2bfloat16(v);
    }
  } else if (b < 76) {                // rope cos/sin table [208][32]
    int idx = (b - 50) * 256 + t;
    if (idx < 208 * 32) {
      int i = idx >> 5, d = idx & 31;
      float inv = exp2f((float)d * -0.41524101186f);
      float a = (float)i * inv;
      ct[idx] = cosf(a);
      st[idx] = sinf(a);
    }
  } else {                            // cls token write
    int idx = (b - 76) * 256 + t;
    if (idx < 8 * Dm) {
      int r = idx / Dm, d = idx - r * Dm;
      act[((size_t)r * NTOK + STOK) * Dm + d] = cls[d];
    }
  }
}

// ---------------- weight convert pack ----------------
// Concat layouts (offsets folded into Bt pointers by host):
//  - wo+wff share [512 n][2080 k] per layer (wo k 0..511, wff k 512..2079)
//  - ca_q+ca_ff1 share [3712 n][416 k] per layer (q rows 0..511, ff1 rows 512..3711)
//  - ca_kv: 4 layers contiguous -> one [512 n][416 k] matrix
struct CvtPack {
  const float* W[11];
  __hip_bfloat16* Bt[11];
};

// convert body: one 64(k) x 128(n) tile, 512 threads (4x float4 loads, 128B row stores).
__device__ void convert_body(int id, float* tile, const CvtPack& p) {
  static const int KK[11]    = {386, 512, 1544, 386, 512, 1544, 386, 386, 512, 386, 1544};
  static const int NN[11]    = {3728, 386, 386, 3728, 386, 386, 512, 128, 386, 3088, 386};
  static const int KPO[11]   = {416, 512, 1568, 416, 512, 1568, 416, 416, 512, 416, 1568};
  static const int KPOUT[11] = {416, 2080, 2080, 416, 2080, 2080, 416, 416, 2080, 416, 2080};
  static const int NTIL[11]  = {30, 4, 4, 30, 4, 4, 4, 1, 4, 25, 4};   // Np/128
  static const int LSTR[11]  = {1597440, 1064960, 1064960, 1597440, 1064960, 1064960,
                                1544192, 53248, 1064960, 1544192, 1064960};
  static const int CNT[11]   = {840, 128, 400, 840, 128, 400, 112, 28, 128, 700, 400};
  int wi = 0;
  while (wi < 10 && id >= CNT[wi]) { id -= CNT[wi]; ++wi; }
  int K = KK[wi], N = NN[wi];
  int ntil = NTIL[wi];
  int kpout = KPOUT[wi];
  int z = id & 3; id >>= 2;
  int kt = id / ntil, bx = id - kt * ntil;
  int k0 = kt * 64, n0 = bx * 128;
  const float* Wl = p.W[wi] + (size_t)z * K * N;
  __hip_bfloat16* Btl = p.Bt[wi] + (size_t)z * LSTR[wi];

  int tid = threadIdx.x;
  bool nfull = (n0 + 128 <= N);

  if (nfull && (N & 3) == 0) {
    int t4 = tid & 31, tk = tid >> 5;
    int nb = n0 + t4 * 4;
    #pragma unroll
    for (int j = 0; j < 4; ++j) {
      int kl = tk + 16 * j;
      int k = k0 + kl;
      float4 v = {0.f, 0.f, 0.f, 0.f};
      if (k < K) v = *(const float4*)(Wl + (size_t)k * N + nb);
      float* tr = tile + kl * 130 + t4 * 4;
      tr[0] = v.x; tr[1] = v.y; tr[2] = v.z; tr[3] = v.w;
    }
  } else {
    int t2 = tid & 63, tk = tid >> 6;
    int nb = n0 + t2 * 2;
    #pragma unroll
    for (int j = 0; j < 8; ++j) {
      int kl = tk + 8 * j;
      int k = k0 + kl;
      float2 v = {0.f, 0.f};
      if (k < K) {
        const float* src = Wl + (size_t)k * N + nb;
        if (nfull) {
          v = *(const float2*)src;
        } else {
          if (nb < N) v.x = src[0];
          if (nb + 1 < N) v.y = src[1];
        }
      }
      tile[kl * 130 + t2 * 2] = v.x;
      tile[kl * 130 + t2 * 2 + 1] = v.y;
    }
  }
  __syncthreads();

  int kv = KPO[wi] - k0; if (kv > 64) kv = 64;
  int tk8 = tid & 7;
  int nr = tid >> 3;
  if (tk8 * 8 < kv) {
    #pragma unroll
    for (int h = 0; h < 2; ++h) {
      int n = nr + 64 * h;
      __hip_bfloat16 out[8] __attribute__((aligned(16)));
      #pragma unroll
      for (int e = 0; e < 8; ++e)
        out[e] = __float2bfloat16(tile[(tk8 * 8 + e) * 130 + n]);
      *(int4*)(Btl + (size_t)(n0 + n) * kpout + k0 + tk8 * 8) = *(const int4*)out;
    }
  }
}

// conv body: one image, 8 waves. patches aliased by pooled (liveness-disjoint).
__device__ void conv_body(int img, char* smem,
                          const float* __restrict__ input, const __hip_bfloat16* __restrict__ wt,
                          const float* __restrict__ conv_b, float* __restrict__ act) {
  __hip_bfloat16* patches = (__hip_bfloat16*)smem;            // [368][40] = 29440
  float* pooled = (float*)smem;                               // [8][400] = 12800 (aliases patches)
  float* biasS = (float*)(smem + 29440);                      // [400] = 1600 (negated bias)

  int bi = img / 400, fi = img % 400;
  int srow = (fi < STOK) ? bi : (4 + bi);
  int tok = (fi < STOK) ? fi : (fi - STOK);
  float* dst = act + ((size_t)srow * NTOK + tok) * Dm;

  int tid = threadIdx.x;
  const float* img_base = input + (size_t)img * 4800;
  for (int i = tid; i < 400; i += 512) biasS[i] = (i < Dm) ? -conv_b[i] : 0.f;

  for (int p = tid; p < 368; p += 512) {
    short rowv[32] __attribute__((aligned(16)));
    #pragma unroll
    for (int k = 27; k < 32; ++k) rowv[k] = 0;
    if (p < 361) {
      int oy = p / 19, ox = p - oy * 19;
      const float* bp = img_base + (2 * oy) * 40 + 2 * ox;
      #pragma unroll
      for (int c = 0; c < 3; ++c) {
        #pragma unroll
        for (int ky = 0; ky < 3; ++ky) {
          const float* rp = bp + c * 1600 + ky * 40;
          #pragma unroll
          for (int kx = 0; kx < 3; ++kx)
            rowv[c * 9 + ky * 3 + kx] = bfb(rp[kx]);
        }
      }
    } else {
      #pragma unroll
      for (int k = 0; k < 27; ++k) rowv[k] = 0;
    }
    int4* dv = (int4*)(patches + p * 40);
    const int4* sv = (const int4*)rowv;
    #pragma unroll
    for (int q = 0; q < 4; ++q) dv[q] = sv[q];
  }
  __syncthreads();

  int lane = tid & 63, w = tid >> 6;
  int col = lane & 15, rgrp = lane >> 4;

  bf16x8 af[3];
  #pragma unroll
  for (int t = 0; t < 3; ++t) {
    int m = w * 3 + t;
    int row = (m < 23) ? (m * 16 + col) : 0;
    af[t] = *(const bf16x8*)&patches[row * 40 + rgrp * 8];
  }
  __syncthreads();   // patches fully consumed into registers; pooled may now overwrite it

  for (int n = 0; n < 25; ++n) {
    bf16x8 bfrag = *(const bf16x8*)&wt[(n * 16 + col) * 32 + rgrp * 8];
    float nb = biasS[n * 16 + col];
    f32x4 a0 = {0.f, 0.f, 0.f, 0.f}, a1 = {0.f, 0.f, 0.f, 0.f};
    a0 = __builtin_amdgcn_mfma_f32_16x16x32_bf16(af[0], bfrag, a0, 0, 0, 0);
    a1 = __builtin_amdgcn_mfma_f32_16x16x32_bf16(af[1], bfrag, a1, 0, 0, 0);
    float psum = 0.f;
    #pragma unroll
    for (int j = 0; j < 4; ++j) psum += fmaxf(a0[j], nb);
    if (w == 7) {
      #pragma unroll
      for (int j = 0; j < 4; ++j) {
        int rr = 352 + rgrp * 4 + j;
        psum += (rr < 361) ? fmaxf(a1[j], nb) : 0.f;
      }
    } else {
      #pragma unroll
      for (int j = 0; j < 4; ++j) psum += fmaxf(a1[j], nb);
      f32x4 a2 = {0.f, 0.f, 0.f, 0.f};
      a2 = __builtin_amdgcn_mfma_f32_16x16x32_bf16(af[2], bfrag, a2, 0, 0, 0);
      #pragma unroll
      for (int j = 0; j < 4; ++j) psum += fmaxf(a2[j], nb);
    }
    psum += __shfl_xor(psum, 16);
    psum += __shfl_xor(psum, 32);
    if (lane < 16) pooled[w * 400 + n * 16 + lane] = psum;
  }
  __syncthreads();
  for (int d = tid; d < Dm; d += 512) {
    float s = 0.f;
    #pragma unroll
    for (int ww = 0; ww < 8; ++ww) s += pooled[ww * 400 + d];
    dst[d] = s * (1.f / 361.f) + conv_b[d];
  }
}

// ---------------- fused prep: conv (1600) + weight convert (4104), interleaved 5:13 ----------------
__global__ __launch_bounds__(512) void prep_conv_kernel(
    CvtPack p, const float* __restrict__ input, const __hip_bfloat16* __restrict__ wt,
    const float* __restrict__ conv_b, float* __restrict__ act) {
  __shared__ __align__(16) char smem[33280];
  int bid = blockIdx.x;
  int g = bid / 18, r = bid - g * 18;
  if (r < 5) {
    conv_body(g * 5 + r, smem, input, wt, conv_b, act);
  } else {
    int cid = g * 13 + (r - 5);
    if (cid < 4104) convert_body(cid, (float*)smem, p);
  }
}

// ---------------- layernorm ----------------
__global__ __launch_bounds__(64) void ln_kernel(const float* __restrict__ x,
                                                const float* __restrict__ g,
                                                __hip_bfloat16* __restrict__ y) {
  size_t row = blockIdx.x;
  const float* xr = x + row * Dm;
  __hip_bfloat16* yr = y + row * 416;
  int t = threadIdx.x;
  float v[7];
  float lsum = 0.f, lsq = 0.f;
  #pragma unroll
  for (int j = 0; j < 7; ++j) {
    int c = t + 64 * j;
    float val = (c < Dm) ? xr[c] : 0.f;
    v[j] = val;
    lsum += val;
    lsq += val * val;
  }
  #pragma unroll
  for (int o = 32; o > 0; o >>= 1) { lsum += __shfl_xor(lsum, o); lsq += __shfl_xor(lsq, o); }
  float mean = lsum * (1.f / 386.f);
  float var = lsq * (1.f / 386.f) - mean * mean;
  float inv = rsqrtf(var + 1e-5f);
  #pragma unroll
  for (int j = 0; j < 7; ++j) {
    int c = t + 64 * j;
    if (c < 416) {
      float out = (c < Dm) ? (v[j] - mean) * inv * g[c] : 0.f;
      yr[c] = __float2bfloat16(out);
    }
  }
}

// ---------------- bf16 MFMA matmul 128x128 ----------------
template<bool ACC>
__global__ __launch_bounds__(256) void mfma_mm(
    const __hip_bfloat16* __restrict__ A, const __hip_bfloat16* __restrict__ Bt,
    float* __restrict__ C, int M, int N, int Kp) {
  __shared__ short As[128 * 32];
  __shared__ short Bs[128 * 32];
  int tid = threadIdx.x;
  int lane = tid & 63, w = tid >> 6;
  int wr = w >> 1, wc = w & 1;
  int bm = blockIdx.y * 128, bn = blockIdx.x * 128;
  f32x4 acc[4][4] = {};

  int sr, sg;
  stage_coords(lane, sr, sg);
  const __hip_bfloat16* Abase = A + (size_t)(bm + w * 16 + sr) * Kp + sg * 8;
  const __hip_bfloat16* Bbase = Bt + (size_t)(bn + w * 16 + sr) * Kp + sg * 8;
  short* AsW1 = As + w * 512;
  short* AsW2 = As + 2048 + w * 512;
  short* BsW1 = Bs + w * 512;
  short* BsW2 = Bs + 2048 + w * 512;
  size_t rstep = (size_t)64 * Kp;
  int key = (lane & 7) << 4;
  int kg16 = (lane >> 4) * 16;

  for (int k0 = 0; k0 < Kp; k0 += 32) {
    gload16(Abase + k0, AsW1);
    gload16(Abase + k0 + rstep, AsW2);
    gload16(Bbase + k0, BsW1);
    gload16(Bbase + k0 + rstep, BsW2);
    __syncthreads();
    bf16x8 af[4], bfr[4];
    #pragma unroll
    for (int m = 0; m < 4; ++m) {
      int R = wr * 64 + m * 16 + (lane & 15);
      af[m] = *(const bf16x8*)((const char*)As + ((R * 64 + kg16) ^ key));
    }
    #pragma unroll
    for (int n = 0; n < 4; ++n) {
      int R = wc * 64 + n * 16 + (lane & 15);
      bfr[n] = *(const bf16x8*)((const char*)Bs + ((R * 64 + kg16) ^ key));
    }
    #pragma unroll
    for (int m = 0; m < 4; ++m)
      #pragma unroll
      for (int n = 0; n < 4; ++n)
        acc[m][n] = __builtin_amdgcn_mfma_f32_16x16x32_bf16(af[m], bfr[n], acc[m][n], 0, 0, 0);
    __syncthreads();
  }

  int col = lane & 15, rbase = (lane >> 4) * 4;
  #pragma unroll
  for (int m = 0; m < 4; ++m) {
    #pragma unroll
    for (int n = 0; n < 4; ++n) {
      #pragma unroll
      for (int j = 0; j < 4; ++j) {
        int gr = bm + wr * 64 + m * 16 + rbase + j;
        int gc = bn + wc * 64 + n * 16 + col;
        if (gr < M && gc < N) {
          size_t idx = (size_t)gr * N + gc;
          if (ACC) C[idx] += acc[m][n][j]; else C[idx] = acc[m][n][j];
        }
      }
    }
  }
}

// ---------------- bf16 MFMA matmul 64x64 (non-ACC, small N) ----------------
__global__ __launch_bounds__(256) void mfma_mm64(
    const __hip_bfloat16* __restrict__ A, const __hip_bfloat16* __restrict__ Bt,
    float* __restrict__ C, int M, int N, int Kp) {
  __shared__ short As[64 * 32];
  __shared__ short Bs[64 * 32];
  int tid = threadIdx.x;
  int lane = tid & 63, w = tid >> 6;
  int wr = w >> 1, wc = w & 1;
  int bm = blockIdx.y * 64, bn = blockIdx.x * 64;
  f32x4 acc[2][2] = {};

  int sr, sg;
  stage_coords(lane, sr, sg);
  const __hip_bfloat16* Abase = A + (size_t)(bm + w * 16 + sr) * Kp + sg * 8;
  const __hip_bfloat16* Bbase = Bt + (size_t)(bn + w * 16 + sr) * Kp + sg * 8;
  short* AsW = As + w * 512;
  short* BsW = Bs + w * 512;
  int key = (lane & 7) << 4;
  int kg16 = (lane >> 4) * 16;

  for (int k0 = 0; k0 < Kp; k0 += 32) {
    gload16(Abase + k0, AsW);
    gload16(Bbase + k0, BsW);
    __syncthreads();
    bf16x8 af[2], bfr[2];
    #pragma unroll
    for (int m = 0; m < 2; ++m) {
      int R = wr * 32 + m * 16 + (lane & 15);
      af[m] = *(const bf16x8*)((const char*)As + ((R * 64 + kg16) ^ key));
    }
    #pragma unroll
    for (int n = 0; n < 2; ++n) {
      int R = wc * 32 + n * 16 + (lane & 15);
      bfr[n] = *(const bf16x8*)((const char*)Bs + ((R * 64 + kg16) ^ key));
    }
    #pragma unroll
    for (int m = 0; m < 2; ++m)
      #pragma unroll
      for (int n = 0; n < 2; ++n)
        acc[m][n] = __builtin_amdgcn_mfma_f32_16x16x32_bf16(af[m], bfr[n], acc[m][n], 0, 0, 0);
    __syncthreads();
  }

  int col = lane & 15, rbase = (lane >> 4) * 4;
  #pragma unroll
  for (int m = 0; m < 2; ++m) {
    #pragma unroll
    for (int n = 0; n < 2; ++n) {
      #pragma unroll
      for (int j = 0; j < 4; ++j) {
        int gr = bm + wr * 32 + m * 16 + rbase + j;
        int gc = bn + wc * 32 + n * 16 + col;
        if (gr < M && gc < N) C[(size_t)gr * N + gc] = acc[m][n][j];
      }
    }
  }
}

// ---------------- split-K 64x64 with atomic accumulate ----------------
__global__ __launch_bounds__(256) void mfma_mm64a(
    const __hip_bfloat16* __restrict__ A, const __hip_bfloat16* __restrict__ Bt,
    float* __restrict__ C, int M, int N, int Kp, int chunk) {
  int kbeg = blockIdx.z * chunk;
  if (kbeg >= Kp) return;
  int kend = min(Kp, kbeg + chunk);
  __shared__ short As[64 * 32];
  __shared__ short Bs[64 * 32];
  int tid = threadIdx.x;
  int lane = tid & 63, w = tid >> 6;
  int wr = w >> 1, wc = w & 1;
  int bm = blockIdx.y * 64, bn = blockIdx.x * 64;
  f32x4 acc[2][2] = {};

  int sr, sg;
  stage_coords(lane, sr, sg);
  const __hip_bfloat16* Abase = A + (size_t)(bm + w * 16 + sr) * Kp + sg * 8;
  const __hip_bfloat16* Bbase = Bt + (size_t)(bn + w * 16 + sr) * Kp + sg * 8;
  short* AsW = As + w * 512;
  short* BsW = Bs + w * 512;
  int key = (lane & 7) << 4;
  int kg16 = (lane >> 4) * 16;

  for (int k0 = kbeg; k0 < kend; k0 += 32) {
    gload16(Abase + k0, AsW);
    gload16(Bbase + k0, BsW);
    __syncthreads();
    bf16x8 af[2], bfr[2];
    #pragma unroll
    for (int m = 0; m < 2; ++m) {
      int R = wr * 32 + m * 16 + (lane & 15);
      af[m] = *(const bf16x8*)((const char*)As + ((R * 64 + kg16) ^ key));
    }
    #pragma unroll
    for (int n = 0; n < 2; ++n) {
      int R = wc * 32 + n * 16 + (lane & 15);
      bfr[n] = *(const bf16x8*)((const char*)Bs + ((R * 64 + kg16) ^ key));
    }
    #pragma unroll
    for (int m = 0; m < 2; ++m)
      #pragma unroll
      for (int n = 0; n < 2; ++n)
        acc[m][n] = __builtin_amdgcn_mfma_f32_16x16x32_bf16(af[m], bfr[n], acc[m][n], 0, 0, 0);
    __syncthreads();
  }

  int col = lane & 15, rbase = (lane >> 4) * 4;
  #pragma unroll
  for (int m = 0; m < 2; ++m) {
    #pragma unroll
    for (int n = 0; n < 2; ++n) {
      #pragma unroll
      for (int j = 0; j < 4; ++j) {
        int gr = bm + wr * 32 + m * 16 + rbase + j;
        int gc = bn + wc * 32 + n * 16 + col;
        if (gr < M && gc < N) unsafeAtomicAdd(&C[(size_t)gr * N + gc], acc[m][n][j]);
      }
    }
  }
}

// ---------------- f32 -> bf16 activation convert with zero K-pad (vectorized) ----------------
__global__ void convert_a_kernel(const float* __restrict__ src, __hip_bfloat16* __restrict__ dst,
                                 int M, int K, int Kp) {
  int chunks = Kp >> 3;
  int idx = blockIdx.x * blockDim.x + threadIdx.x;
  if (idx >= M * chunks) return;
  int r = idx / chunks, ch = idx - r * chunks;
  int c = ch * 8;
  const float* sr = src + (size_t)r * K;
  __hip_bfloat16 out[8] __attribute__((aligned(16)));
  #pragma unroll
  for (int e = 0; e < 8; e += 2) {
    int cc = c + e;
    float2 v = {0.f, 0.f};
    if (cc + 1 < K) v = *(const float2*)(sr + cc);
    else if (cc < K) v.x = sr[cc];
    out[e] = __float2bfloat16(v.x);
    out[e + 1] = __float2bfloat16(v.y);
  }
  *(int4*)(dst + (size_t)r * Kp + c) = *(const int4*)out;
}

// ---------------- fused flash attention + silu (both consume the QKVFF GEMM output) ----------------
// Blocks [0, 26*nb): attention (O cols 0..511 of ahbuf). Blocks [26*nb, ...): silu
// (cols 512..2079). Silu source = Q/qstride; silu dst = O+512 stride ostride.
__global__ __launch_bounds__(256) void attn_silu_kernel(
    const float* __restrict__ Q, int qstride,
    const float* __restrict__ K, int kstride,
    const float* __restrict__ V, int vstride,
    __hip_bfloat16* __restrict__ O, int ostride,
    int causal, float scale,
    const float* __restrict__ ct, const float* __restrict__ st, int dorope,
    int nb, int rows, int x1off, int gateoff) {
  int nf = 26 * nb;
  int tid = threadIdx.x;

  if ((int)blockIdx.x >= nf) {
    // ---- silu role ----
    int idx = ((int)blockIdx.x - nf) * 256 + tid;
    if (idx >= rows * 196) return;
    int r = idx / 196, ch = idx - r * 196;
    int c = ch * 8;
    __hip_bfloat16 out[8] __attribute__((aligned(16)));
    if (c < FFf) {
      const float* sr = Q + (size_t)r * qstride;
      float4 xa = *(const float4*)(sr + x1off + c);
      float4 xb = *(const float4*)(sr + x1off + c + 4);
      float4 ga = *(const float4*)(sr + gateoff + c);
      float4 gb = *(const float4*)(sr + gateoff + c + 4);
      float xv[8] = {xa.x, xa.y, xa.z, xa.w, xb.x, xb.y, xb.z, xb.w};
      float gv[8] = {ga.x, ga.y, ga.z, ga.w, gb.x, gb.y, gb.z, gb.w};
      #pragma unroll
      for (int e = 0; e < 8; ++e) {
        float g = gv[e];
        out[e] = __float2bfloat16(g / (1.f + __expf(-g)) * xv[e]);
      }
    } else {
      #pragma unroll
      for (int e = 0; e < 8; ++e) out[e] = __float2bfloat16(0.f);
    }
    *(int4*)(O + 512 + (size_t)r * ostride + c) = *(const int4*)out;
    return;
  }

  // ---- attention role ----
  __shared__ __align__(16) char smembuf[59392];
  short* Ks  = (short*)smembuf;            // [208*64]   = 26624 B (dead after S loop)
  short* Ps  = (short*)smembuf;            // [4*16*232] = 29696 B (aliases Ks)
  short* VTs = (short*)(smembuf + 29696);  // [64*232]   = 29696 B

  int bb = blockIdx.x / 26;
  int i0 = (blockIdx.x % 26) * 8;
  int lane = tid & 63, w = tid >> 6;
  const float* Qb = Q + (size_t)bb * NTOK * qstride;
  const float* Kb = K + (size_t)bb * NTOK * kstride;
  const float* Vb = V + (size_t)bb * NTOK * vstride;

  int ntiles = causal ? min(13, (i0 + 7) / 16 + 1) : 13;
  int jstage = ntiles * 16;
  int jm = min(jstage, 201);

  {
    int4 z = {0, 0, 0, 0};
    int4* vt4 = (int4*)VTs;
    for (int idx = tid; idx < 64 * 232 * 2 / 16; idx += 256) vt4[idx] = z;
  }
  __syncthreads();

  for (int jj = tid >> 2; jj < jstage; jj += 64) {
    int q4 = tid & 3;
    int dbase = q4 * 16;
    const float* kro = Kb + (size_t)jj * kstride;
    float selfv[16], partv[16];
    #pragma unroll
    for (int f = 0; f < 4; ++f) {
      float4 kv = {0.f, 0.f, 0.f, 0.f};
      if (jj < 201) kv = ((const float4*)(kro + dbase))[f];
      selfv[f * 4 + 0] = kv.x; selfv[f * 4 + 1] = kv.y;
      selfv[f * 4 + 2] = kv.z; selfv[f * 4 + 3] = kv.w;
    }
    if (dorope && jj < 201) {
      int pbase = dbase ^ 32;
      #pragma unroll
      for (int f = 0; f < 4; ++f) {
        float4 kv = ((const float4*)(kro + pbase))[f];
        partv[f * 4 + 0] = kv.x; partv[f * 4 + 1] = kv.y;
        partv[f * 4 + 2] = kv.z; partv[f * 4 + 3] = kv.w;
      }
      const float* cr = ct + jj * 32 + (dbase & 31);
      const float* sr2 = st + jj * 32 + (dbase & 31);
      #pragma unroll
      for (int e = 0; e < 16; ++e) {
        float c = cr[e], s = sr2[e];
        selfv[e] = (dbase < 32) ? (selfv[e] * c - partv[e] * s)
                                : (selfv[e] * c + partv[e] * s);
      }
    }
    #pragma unroll
    for (int f = 0; f < 4; ++f) {
      short4 b;
      b.x = bfb(selfv[f * 4 + 0]); b.y = bfb(selfv[f * 4 + 1]);
      b.z = bfb(selfv[f * 4 + 2]); b.w = bfb(selfv[f * 4 + 3]);
      int colb = dbase * 2 + f * 8;
      *(short4*)((char*)Ks + (jj * 128 + (colb ^ ((jj & 7) << 4)))) = b;
    }
  }
  for (int jj = tid >> 3; jj < jm; jj += 32) {
    int e8 = (tid & 7) * 8;
    const float4* vr = (const float4*)(Vb + (size_t)jj * vstride + e8);
    float4 v0 = vr[0], v1 = vr[1];
    float vv[8] = {v0.x, v0.y, v0.z, v0.w, v1.x, v1.y, v1.z, v1.w};
    #pragma unroll
    for (int e = 0; e < 8; ++e) VTs[(e8 + e) * 232 + jj] = bfb(vv[e]);
  }

  int r = lane & 15, kg = lane >> 4;
  int rg = w * 16 + r;
  int iq = i0 + (rg >> 3);
  if (iq > 200) iq = 200;
  int h = rg & 7;
  const float* qr = Qb + (size_t)iq * qstride + h * 64 + kg * 8;
  float x1[8], x2[8];
  {
    float4 a0 = ((const float4*)qr)[0];
    float4 a1 = ((const float4*)(qr + 4))[0];
    float4 b0 = ((const float4*)(qr + 32))[0];
    float4 b1 = ((const float4*)(qr + 36))[0];
    x1[0] = a0.x; x1[1] = a0.y; x1[2] = a0.z; x1[3] = a0.w;
    x1[4] = a1.x; x1[5] = a1.y; x1[6] = a1.z; x1[7] = a1.w;
    x2[0] = b0.x; x2[1] = b0.y; x2[2] = b0.z; x2[3] = b0.w;
    x2[4] = b1.x; x2[5] = b1.y; x2[6] = b1.z; x2[7] = b1.w;
  }
  if (dorope) {
    const float* cr = ct + iq * 32 + kg * 8;
    const float* sr2 = st + iq * 32 + kg * 8;
    #pragma unroll
    for (int e = 0; e < 8; ++e) {
      float c = cr[e], s = sr2[e];
      float n1 = x1[e] * c - x2[e] * s;
      float n2 = x2[e] * c + x1[e] * s;
      x1[e] = n1; x2[e] = n2;
    }
  }
  bf16x8 aq[2];
  #pragma unroll
  for (int e = 0; e < 8; ++e) {
    aq[0][e] = bfb(x1[e] * scale);
    aq[1][e] = bfb(x2[e] * scale);
  }
  __syncthreads();

  int key = (lane & 7) << 4;
  f32x4 s[13];
  #pragma unroll
  for (int nt = 0; nt < 13; ++nt) {
    s[nt] = (f32x4){0.f, 0.f, 0.f, 0.f};
    if (nt < ntiles) {
      #pragma unroll
      for (int kt = 0; kt < 2; ++kt) {
        int row = nt * 16 + r;
        bf16x8 bk = *(const bf16x8*)((const char*)Ks + ((row * 128 + kt * 64 + kg * 16) ^ key));
        s[nt] = __builtin_amdgcn_mfma_f32_16x16x32_bf16(aq[kt], bk, s[nt], 0, 0, 0);
      }
    }
  }

  int jcol = lane & 15;
  int ibase[4];
  #pragma unroll
  for (int reg = 0; reg < 4; ++reg) ibase[reg] = i0 + ((w * 16 + kg * 4 + reg) >> 3);

  f32x4 mx = {-1e30f, -1e30f, -1e30f, -1e30f};
  #pragma unroll
  for (int nt = 0; nt < 13; ++nt) {
    if (nt >= ntiles) continue;
    int j = nt * 16 + jcol;
    #pragma unroll
    for (int reg = 0; reg < 4; ++reg) {
      bool ok = (j <= 200) && (!causal || j <= ibase[reg]);
      float sv = ok ? s[nt][reg] : -1e30f;
      s[nt][reg] = sv;
      mx[reg] = fmaxf(mx[reg], sv);
    }
  }
  #pragma unroll
  for (int o = 1; o < 16; o <<= 1) {
    #pragma unroll
    for (int reg = 0; reg < 4; ++reg) mx[reg] = fmaxf(mx[reg], __shfl_xor(mx[reg], o));
  }
  f32x4 sm = {0.f, 0.f, 0.f, 0.f};
  #pragma unroll
  for (int nt = 0; nt < 13; ++nt) {
    if (nt >= ntiles) continue;
    #pragma unroll
    for (int reg = 0; reg < 4; ++reg) {
      float p = __expf(s[nt][reg] - mx[reg]);
      s[nt][reg] = p;
      sm[reg] += p;
    }
  }
  #pragma unroll
  for (int o = 1; o < 16; o <<= 1) {
    #pragma unroll
    for (int reg = 0; reg < 4; ++reg) sm[reg] += __shfl_xor(sm[reg], o);
  }
  f32x4 inv;
  #pragma unroll
  for (int reg = 0; reg < 4; ++reg) inv[reg] = 1.f / sm[reg];

  __syncthreads();   // all warps done reading Ks; Ps (aliased) may now be written

  short* Pw = Ps + w * 16 * 232;
  #pragma unroll
  for (int nt = 0; nt < 13; ++nt) {
    #pragma unroll
    for (int reg = 0; reg < 4; ++reg) {
      float p = (nt < ntiles) ? s[nt][reg] * inv[reg] : 0.f;
      Pw[(kg * 4 + reg) * 232 + nt * 16 + jcol] = bfb(p);
    }
  }
  #pragma unroll
  for (int e = 0; e < 4; ++e) Pw[r * 232 + 208 + kg * 4 + e] = 0;

  int ktn = (jstage + 31) >> 5;
  f32x4 o[4] = {};
  #pragma unroll
  for (int kt = 0; kt < 7; ++kt) {
    if (kt >= ktn) continue;
    bf16x8 ap = *(const bf16x8*)((const char*)Pw + (r * 464 + kt * 64 + kg * 16));
    #pragma unroll
    for (int nt = 0; nt < 4; ++nt) {
      bf16x8 bv = *(const bf16x8*)((const char*)VTs + ((nt * 16 + r) * 464 + kt * 64 + kg * 16));
      o[nt] = __builtin_amdgcn_mfma_f32_16x16x32_bf16(ap, bv, o[nt], 0, 0, 0);
    }
  }

  #pragma unroll
  for (int nt = 0; nt < 4; ++nt) {
    #pragma unroll
    for (int reg = 0; reg < 4; ++reg) {
      int rc = w * 16 + kg * 4 + reg;
      int i = i0 + (rc >> 3);
      if (i < NTOK) {
        int hh = rc & 7;
        O[((size_t)bb * NTOK + i) * ostride + hh * 64 + nt * 16 + jcol] = __float2bfloat16(o[nt][reg]);
      }
    }
  }
}

// ---------------- head ----------------
__global__ __launch_bounds__(64) void head_kernel(const float* __restrict__ act,
                                                  const float* __restrict__ g,
                                                  const float* __restrict__ w,
                                                  float* __restrict__ out) {
  int bb = blockIdx.x;
  const float* xr = act + ((size_t)bb * NTOK + STOK) * Dm;
  int t = threadIdx.x;
  float v[7];
  float lsum = 0.f, lsq = 0.f;
  #pragma unroll
  for (int j = 0; j < 7; ++j) {
    int c = t + 64 * j;
    float val = (c < Dm) ? xr[c] : 0.f;
    v[j] = val;
    lsum += val;
    lsq += val * val;
  }
  #pragma unroll
  for (int o = 32; o > 0; o >>= 1) { lsum += __shfl_xor(lsum, o); lsq += __shfl_xor(lsq, o); }
  float mean = lsum * (1.f / 386.f);
  float var = lsq * (1.f / 386.f) - mean * mean;
  float inv = rsqrtf(var + 1e-5f);
  float d0 = 0.f, d1 = 0.f;
  #pragma unroll
  for (int j = 0; j < 7; ++j) {
    int c = t + 64 * j;
    if (c < Dm) {
      float xn = (v[j] - mean) * inv * g[c];
      d0 = fmaf(xn, w[2 * c], d0);
      d1 = fmaf(xn, w[2 * c + 1], d1);
    }
  }
  #pragma unroll
  for (int o = 32; o > 0; o >>= 1) { d0 += __shfl_xor(d0, o); d1 += __shfl_xor(d1, o); }
  if (t == 0) { out[2 * bb] = d0; out[2 * bb + 1] = d1; }
}

extern "C" void kernel_launch(void* const* d_in, const int* in_sizes, int n_in,
                              void* d_out, int out_size, void* d_ws, size_t ws_size,
                              hipStream_t stream) {
  const float* input     = (const float*)d_in[0];
  const float* conv_w    = (const float*)d_in[1];
  const float* conv_b    = (const float*)d_in[2];
  const float* cls_tok   = (const float*)d_in[3];
  const float* uni_ln    = (const float*)d_in[4];
  const float* uni_fused = (const float*)d_in[5];
  const float* uni_wo    = (const float*)d_in[6];
  const float* uni_wff   = (const float*)d_in[7];
  const float* mm_ln     = (const float*)d_in[8];
  const float* mm_fused  = (const float*)d_in[9];
  const float* mm_wo     = (const float*)d_in[10];
  const float* mm_wff    = (const float*)d_in[11];
  const float* ca_ln     = (const float*)d_in[12];
  const float* ca_q      = (const float*)d_in[13];
  const float* ca_kv     = (const float*)d_in[14];
  const float* ca_o      = (const float*)d_in[15];
  const float* ca_ff1    = (const float*)d_in[16];
  const float* ca_ff2    = (const float*)d_in[17];
  const float* logit_ln  = (const float*)d_in[18];
  const float* logit_w   = (const float*)d_in[19];
  (void)in_sizes; (void)n_in; (void)out_size; (void)ws_size;

  char* wsb = (char*)d_ws;
  size_t off = 0;
  auto alloc = [&](size_t bytes) { void* p = wsb + off; off += (bytes + 255) & ~(size_t)255; return p; };

  float* act   = (float*)alloc((size_t)8 * NTOK * Dm * 4);
  float* fbuf  = (float*)alloc((size_t)8 * NTOK * FUS * 4);
  float* kvall = (float*)alloc((size_t)4 * NTOK * 512 * 4);
  float* ctab  = (float*)alloc((size_t)208 * 32 * 4);
  float* stab  = (float*)alloc((size_t)208 * 32 * 4);
  __hip_bfloat16* xnb   = (__hip_bfloat16*)alloc((size_t)1664 * 416 * 2);
  __hip_bfloat16* ahbuf = (__hip_bfloat16*)alloc((size_t)1664 * 2080 * 2);  // [attn(512) | silu(1568)]
  __hip_bfloat16* ctxb  = (__hip_bfloat16*)alloc((size_t)896 * 416 * 2);
  __hip_bfloat16* cwT   = (__hip_bfloat16*)alloc((size_t)400 * 32 * 2);

  size_t sF  = (size_t)3840 * 416;      // fused qkvff weights (uni/mm)
  size_t sOW = (size_t)512 * 2080;      // wo|wff K-concat per layer
  size_t sQF = (size_t)3712 * 416;      // ca q|ff1 N-concat per layer
  __hip_bfloat16* uF  = (__hip_bfloat16*)alloc(4 * sF * 2);
  __hip_bfloat16* uOW = (__hip_bfloat16*)alloc(4 * sOW * 2);
  __hip_bfloat16* mF  = (__hip_bfloat16*)alloc(4 * sF * 2);
  __hip_bfloat16* mOW = (__hip_bfloat16*)alloc(4 * sOW * 2);
  __hip_bfloat16* cQF = (__hip_bfloat16*)alloc(4 * sQF * 2);
  __hip_bfloat16* cKV = (__hip_bfloat16*)alloc((size_t)512 * 416 * 2);   // 4 layers contiguous
  __hip_bfloat16* cOF = (__hip_bfloat16*)alloc(4 * sOW * 2);

  CvtPack pk;
  pk.W[0] = uni_fused; pk.Bt[0] = uF;
  pk.W[1] = uni_wo;    pk.Bt[1] = uOW;
  pk.W[2] = uni_wff;   pk.Bt[2] = uOW + 512;        // K-offset 512 within 2080 rows
  pk.W[3] = mm_fused;  pk.Bt[3] = mF;
  pk.W[4] = mm_wo;     pk.Bt[4] = mOW;
  pk.W[5] = mm_wff;    pk.Bt[5] = mOW + 512;
  pk.W[6] = ca_q;      pk.Bt[6] = cQF;
  pk.W[7] = ca_kv;     pk.Bt[7] = cKV;
  pk.W[8] = ca_o;      pk.Bt[8] = cOF;
  pk.W[9] = ca_ff1;    pk.Bt[9] = cQF + (size_t)512 * 416;  // N-offset 512 rows
  pk.W[10] = ca_ff2;   pk.Bt[10] = cOF + 512;

  misc_prep_kernel<<<89, 256, 0, stream>>>(conv_w, cwT, ctab, stab, cls_tok, act);
  prep_conv_kernel<<<5760, 512, 0, stream>>>(pk, input, cwT, conv_b, act);

  auto mmW = [&](const __hip_bfloat16* A, const __hip_bfloat16* Bt, float* C,
                 int M, int N, int Kp) {
    if (N <= 512) {
      dim3 g((N + 63) / 64, (M + 63) / 64);
      mfma_mm64<<<g, 256, 0, stream>>>(A, Bt, C, M, N, Kp);
    } else {
      dim3 g((N + 127) / 128, (M + 127) / 128);
      mfma_mm<false><<<g, 256, 0, stream>>>(A, Bt, C, M, N, Kp);
    }
  };
  auto mmA = [&](const __hip_bfloat16* A, const __hip_bfloat16* Bt, float* C,
                 int M, int N, int Kp) {
    int gx = (N + 63) / 64, gy = (M + 63) / 64;
    int blocks = gx * gy;
    int ksteps = Kp / 32;
    int nz = (blocks >= 512) ? 1 : (512 + blocks - 1) / blocks;
    if (nz > ksteps) nz = ksteps;
    int chunk = ((ksteps + nz - 1) / nz) * 32;
    dim3 g(gx, gy, nz);
    mfma_mm64a<<<g, 256, 0, stream>>>(A, Bt, C, M, N, Kp, chunk);
  };

  // per-transformer-block: ln -> QKVFF GEMM -> fused {fattn | silu} -> one K-concat mmA
  auto run_ptb = [&](float* x, int nb, const float* g, const __hip_bfloat16* wfB,
                     const __hip_bfloat16* owB) {
    int M = nb * NTOK;
    ln_kernel<<<M, 64, 0, stream>>>(x, g, xnb);
    mmW(xnb, wfB, fbuf, M, FUS, 416);
    int nblk = 26 * nb + (M * 196 + 255) / 256;
    attn_silu_kernel<<<nblk, 256, 0, stream>>>(
        fbuf, FUS, fbuf + 512, FUS, fbuf + 576, FUS, ahbuf, 2080, 1, 0.125f,
        ctab, stab, 1, nb, M, 640, 2184);
    mmA(ahbuf, owB, x, M, Dm, 2080);
  };

  for (int i = 0; i < 4; ++i)
    run_ptb(act, 8, uni_ln + i * Dm, uF + i * sF, uOW + i * sOW);

  const float* ctx = act + (size_t)4 * NTOK * Dm;
  convert_a_kernel<<<(804 * 52 + 255) / 256, 256, 0, stream>>>(ctx, ctxb, 804, Dm, 416);
  // all 4 layers' kv projections in one GEMM: kvall[m][i*128 + j]
  mmW(ctxb, cKV, kvall, 804, 512, 416);

  for (int i = 0; i < 4; ++i) {
    run_ptb(act, 4, mm_ln + i * Dm, mF + i * sF, mOW + i * sOW);
    int M = 4 * NTOK;
    ln_kernel<<<M, 64, 0, stream>>>(act, ca_ln + i * Dm, xnb);
    // q (cols 0..511) and ff1 (cols 512..3711) in one N=3712 GEMM
    mmW(xnb, cQF + i * sQF, fbuf, M, 3712, 416);
    int nblk = 26 * 4 + (M * 196 + 255) / 256;
    attn_silu_kernel<<<nblk, 256, 0, stream>>>(
        fbuf, 3712, kvall + i * 128, 512, kvall + i * 128 + 64, 512, ahbuf, 2080,
        0, 0.125f, ctab, stab, 0, 4, M, 512, 2056);
    mmA(ahbuf, cOF + i * sOW, act, M, Dm, 2080);
  }

  head_kernel<<<4, 64, 0, stream>>>(act, logit_ln, logit_w, (float*)d_out);
}